// Round 6
// baseline (413.461 us; speedup 1.0000x reference)
//
#include <hip/hip_runtime.h>
#include <hip/hip_bf16.h>

#define BATCH 65536
#define DK 512
#define DV 512
#define DH 64
#define BM 64
#define NT (DV / 16)   // 32 column-iterations

typedef __attribute__((ext_vector_type(8))) short bf16x8;
typedef __attribute__((ext_vector_type(4))) float f32x4;

// bf16 weights: [0]=W1 (64x512), [32768]=W2 (512x64), [65536]=Wp (512x512)
__device__ short g_wb[327680];

__device__ __forceinline__ short f2bf(float f) {
    union { __hip_bfloat16 h; short s; } u;
    u.h = __float2bfloat16(f);
    return u.s;
}

__global__ __launch_bounds__(256) void conv_weights(
    const float* __restrict__ W1, const float* __restrict__ W2,
    const float* __restrict__ Wp)
{
    int i = blockIdx.x * 256 + threadIdx.x;     // 81920 threads x 4 elems
    long off = (long)i * 4;
    const float* src;
    if (off < 32768)       src = W1 + off;
    else if (off < 65536)  src = W2 + (off - 32768);
    else                   src = Wp + (off - 65536);
    float4 v = *reinterpret_cast<const float4*>(src);
    short4 s;
    s.x = f2bf(v.x); s.y = f2bf(v.y); s.z = f2bf(v.z); s.w = f2bf(v.w);
    *reinterpret_cast<short4*>(g_wb + off) = s;
}

// ---- reg-staging helpers for a 16-row x 512-col bf16 tile (16 KB) ----
struct StReg { bf16x8 v[4]; };

__device__ __forceinline__ StReg stage_load(const short* __restrict__ src, int tid) {
    StReg s;
    #pragma unroll
    for (int ld = 0; ld < 4; ++ld)
        s.v[ld] = *reinterpret_cast<const bf16x8*>(
            reinterpret_cast<const char*>(src) + ld * 4096 + tid * 16);
    return s;
}

__device__ __forceinline__ void stage_write(char* buf, const StReg& s, int tid) {
    #pragma unroll
    for (int ld = 0; ld < 4; ++ld) {
        int o = ld * 4096 + tid * 16;
        int w = o ^ (((o >> 10) & 7) << 4);   // XOR-swizzle (row period 1024B)
        *reinterpret_cast<bf16x8*>(buf + w) = s.v[ld];
    }
}

// LDS offsets within the 36864-byte block (fits 4 blocks/CU: 4*36864 <= 160K)
#define WPA 0
#define WPB 16384
#define W2A 32768
#define W2B (32768 + 2048)

__global__ __launch_bounds__(256, 4) void fused_free_energy(
    const float* __restrict__ key, const float* __restrict__ value,
    const float* __restrict__ b1, const float* __restrict__ b2,
    const float* __restrict__ pb,
    float* __restrict__ outF, float* __restrict__ outPred,
    float* __restrict__ outPrec, float* __restrict__ outErr)
{
    __shared__ __align__(16) char lds[36864];

    const short* W1b = g_wb;
    const short* W2b = g_wb + 32768;
    const short* Wpb = g_wb + 65536;

    const int tid  = threadIdx.x;
    const int wave = tid >> 6;
    const int lane = tid & 63;
    const int lh   = lane & 15;
    const int lg   = lane >> 4;
    const long row0 = (long)blockIdx.x * BM;

    // ---- prologue: key rows -> bf16 register fragments (via LDS, 2 chunks of 32 rows) ----
    bf16x8 kreg[16];
    #pragma unroll
    for (int c = 0; c < 2; ++c) {
        const float4* kin = reinterpret_cast<const float4*>(key + (row0 + c * 32) * DK);
        #pragma unroll
        for (int i = 0; i < 16; ++i) {          // 32 rows x 128 float4 / 256 thr
            int idx = i * 256 + tid;
            int r = idx >> 7, c4 = idx & 127;
            float4 v = kin[idx];
            short4 s;
            s.x = f2bf(v.x); s.y = f2bf(v.y); s.z = f2bf(v.z); s.w = f2bf(v.w);
            int byte = (r * 1024 + c4 * 8) ^ ((r & 7) << 4);
            *reinterpret_cast<short4*>(lds + byte) = s;
        }
        __syncthreads();
        if ((wave >> 1) == c) {
            int rr = (wave & 1) * 16 + lh;
            #pragma unroll
            for (int kk = 0; kk < 16; ++kk) {
                int byte = (rr * 1024 + kk * 64 + lg * 16) ^ ((rr & 7) << 4);
                kreg[kk] = *reinterpret_cast<const bf16x8*>(lds + byte);
            }
        }
        __syncthreads();
    }

    const f32x4 zf = {0.f, 0.f, 0.f, 0.f};

    // ---- GEMM1: h = gelu(key @ W1^T + b1), swapped operands; h kept in regs ----
    short hs_all[16];   // h[own row][jt*16 + lg*4 + r] for jt=0..3, r=0..3
    {
        StReg st = stage_load(W1b, tid);
        stage_write(lds + WPA, st, tid);
        __syncthreads();
        #pragma unroll
        for (int jt = 0; jt < 4; ++jt) {
            char* cbuf = lds + ((jt & 1) ? WPB : WPA);
            StReg nx;
            if (jt < 3) nx = stage_load(W1b + (jt + 1) * 16 * DK, tid);
            f32x4 acc = zf;
            #pragma unroll
            for (int kk = 0; kk < 16; ++kk) {
                int byte = (lh * 1024 + kk * 64 + lg * 16) ^ ((lh & 7) << 4);
                bf16x8 af = *reinterpret_cast<const bf16x8*>(cbuf + byte);
                acc = __builtin_amdgcn_mfma_f32_16x16x32_bf16(af, kreg[kk], acc, 0, 0, 0);
            }
            float4 b1v = *reinterpret_cast<const float4*>(b1 + jt * 16 + lg * 4);
            float b1a[4] = {b1v.x, b1v.y, b1v.z, b1v.w};
            #pragma unroll
            for (int r = 0; r < 4; ++r) {
                float z = acc[r] + b1a[r];
                float g = 0.5f * z * (1.0f + erff(z * 0.70710678f));  // exact GELU
                hs_all[jt * 4 + r] = f2bf(g);
            }
            if (jt < 3) stage_write(lds + ((jt & 1) ? WPA : WPB), nx, tid);
            __syncthreads();
        }
        // park h in WPA (wave-private 2KB slots), convert to B-fragment layout
        #pragma unroll
        for (int jt = 0; jt < 4; ++jt) {
            int hb = WPA + wave * 2048 + ((lh * 128 + jt * 32 + lg * 8) ^ ((lh & 7) << 4));
            short4 hv = {hs_all[jt * 4 + 0], hs_all[jt * 4 + 1],
                         hs_all[jt * 4 + 2], hs_all[jt * 4 + 3]};
            *reinterpret_cast<short4*>(lds + hb) = hv;
        }
        __syncthreads();
    }

    bf16x8 hreg[2];
    #pragma unroll
    for (int kh = 0; kh < 2; ++kh) {
        int byte = (lh * 128 + kh * 64 + lg * 16) ^ ((lh & 7) << 4);
        hreg[kh] = *reinterpret_cast<const bf16x8*>(lds + WPA + wave * 2048 + byte);
    }
    __syncthreads();   // before main staging overwrites WPA

    // ---- main loop: 32 iterations of 16 output columns ----
    {
        StReg st = stage_load(Wpb, tid);
        const bool w2a = (tid < 128);
        bf16x8 w2r;
        if (w2a) w2r = *reinterpret_cast<const bf16x8*>(
                     reinterpret_cast<const char*>(W2b) + tid * 16);
        stage_write(lds + WPA, st, tid);
        if (w2a) {
            int o = tid * 16;
            *reinterpret_cast<bf16x8*>(lds + W2A + (o ^ (((o >> 7) & 7) << 4))) = w2r;
        }
        __syncthreads();

        float facc = 0.f;
        const long grow = row0 + wave * 16 + lh;
        float4 sv_pr, sv_pc, sv_er;           // even-iteration results (write-combine)
        long sv_ga = 0;

        for (int it = 0; it < NT; ++it) {
            char* wpc = lds + ((it & 1) ? WPB : WPA);
            char* w2c = lds + ((it & 1) ? W2B : W2A);

            // issue next-tile global loads early (hide L2 latency under compute)
            StReg nx; bf16x8 w2n;
            if (it + 1 < NT) {
                nx = stage_load(Wpb + (it + 1) * 16 * DK, tid);
                if (w2a) w2n = *reinterpret_cast<const bf16x8*>(
                             reinterpret_cast<const char*>(W2b) + (it + 1) * 2048 + tid * 16);
            }

            // GEMM3: z3 tile, A = Wp rows (n) from LDS, B = key rows (m) from regs
            f32x4 acc3 = zf;
            #pragma unroll
            for (int kk = 0; kk < 16; ++kk) {
                int byte = (lh * 1024 + kk * 64 + lg * 16) ^ ((lh & 7) << 4);
                bf16x8 af = *reinterpret_cast<const bf16x8*>(wpc + byte);
                acc3 = __builtin_amdgcn_mfma_f32_16x16x32_bf16(af, kreg[kk], acc3, 0, 0, 0);
            }
            // GEMM2: pred tile, A = W2 from LDS, B = h from regs
            f32x4 acc2 = zf;
            #pragma unroll
            for (int kh = 0; kh < 2; ++kh) {
                int byte = (lh * 128 + kh * 64 + lg * 16) ^ ((lh & 7) << 4);
                bf16x8 af = *reinterpret_cast<const bf16x8*>(w2c + byte);
                acc2 = __builtin_amdgcn_mfma_f32_16x16x32_bf16(af, hreg[kh], acc2, 0, 0, 0);
            }

            // epilogue: lane holds 4 consecutive cols (n = it*16 + lg*4 + r) of row grow
            int nb = it * 16 + lg * 4;
            float4 b2v = *reinterpret_cast<const float4*>(b2 + nb);
            float4 pbv = *reinterpret_cast<const float4*>(pb + nb);
            float b2a[4] = {b2v.x, b2v.y, b2v.z, b2v.w};
            float pba[4] = {pbv.x, pbv.y, pbv.z, pbv.w};
            long ga = grow * DV + nb;
            float4 val = *reinterpret_cast<const float4*>(value + ga);
            float va[4] = {val.x, val.y, val.z, val.w};
            float prv[4], pcv[4], erv[4];
            #pragma unroll
            for (int r = 0; r < 4; ++r) {
                float pred = acc2[r] + b2a[r];
                float z    = acc3[r] + pba[r];
                // softplus via HW exp/log: arg of log in (1,2], abs err ~1e-7
                float prec = fmaxf(z, 0.f) + __logf(1.0f + __expf(-fabsf(z))) + 0.01f;
                float err  = fminf(fmaxf(va[r] - pred, -3.f), 3.f);
                prv[r] = pred; pcv[r] = prec; erv[r] = err;
                facc += prec * err * err - __logf(prec);
            }
            float4 pr4 = {prv[0], prv[1], prv[2], prv[3]};
            float4 pc4 = {pcv[0], pcv[1], pcv[2], pcv[3]};
            float4 er4 = {erv[0], erv[1], erv[2], erv[3]};
            if ((it & 1) == 0) {
                sv_pr = pr4; sv_pc = pc4; sv_er = er4; sv_ga = ga;
            } else {
                // write both halves of each 128B line adjacently -> full-line writeback
                *reinterpret_cast<float4*>(outPred + sv_ga) = sv_pr;
                *reinterpret_cast<float4*>(outPred + ga)    = pr4;
                *reinterpret_cast<float4*>(outPrec + sv_ga) = sv_pc;
                *reinterpret_cast<float4*>(outPrec + ga)    = pc4;
                *reinterpret_cast<float4*>(outErr  + sv_ga) = sv_er;
                *reinterpret_cast<float4*>(outErr  + ga)    = er4;
            }

            // write next tile into the other buffer (its readers finished last barrier)
            if (it + 1 < NT) {
                stage_write(lds + ((it & 1) ? WPA : WPB), nx, tid);
                if (w2a) {
                    int o = tid * 16;
                    *reinterpret_cast<bf16x8*>(
                        lds + ((it & 1) ? W2A : W2B) + (o ^ (((o >> 7) & 7) << 4))) = w2n;
                }
            }
            __syncthreads();
        }

        // F: sum the 4 lg-lanes holding the same row
        facc += __shfl_xor(facc, 16, 64);
        facc += __shfl_xor(facc, 32, 64);
        if (lane < 16) outF[grow] = facc * (1.0f / 512.0f);
    }
}

extern "C" void kernel_launch(void* const* d_in, const int* in_sizes, int n_in,
                              void* d_out, int out_size, void* d_ws, size_t ws_size,
                              hipStream_t stream) {
    const float* key   = (const float*)d_in[0];
    const float* value = (const float*)d_in[1];
    const float* W1    = (const float*)d_in[2];
    const float* b1    = (const float*)d_in[3];
    const float* W2    = (const float*)d_in[4];
    const float* b2    = (const float*)d_in[5];
    const float* Wp    = (const float*)d_in[6];
    const float* pb    = (const float*)d_in[7];

    float* outF    = (float*)d_out;
    float* outPred = outF + BATCH;
    float* outPrec = outPred + (long)BATCH * DV;
    float* outErr  = outPrec + (long)BATCH * DV;

    conv_weights<<<320, 256, 0, stream>>>(W1, W2, Wp);
    fused_free_energy<<<BATCH / BM, 256, 0, stream>>>(key, value, b1, b2, pb,
                                                      outF, outPred, outPrec, outErr);
}

// Round 7
// 413.041 us; speedup vs baseline: 1.0010x; 1.0010x over previous
//
#include <hip/hip_runtime.h>
#include <hip/hip_bf16.h>

#define BATCH 65536
#define DK 512
#define DV 512
#define DH 64
#define BM 64
#define NT (DV / 16)   // 32 column-iterations

typedef __attribute__((ext_vector_type(8))) short bf16x8;
typedef __attribute__((ext_vector_type(4))) float f32x4;

// bf16 weights: [0]=W1 (64x512), [32768]=W2 (512x64), [65536]=Wp (512x512)
__device__ short g_wb[327680];

__device__ __forceinline__ short f2bf(float f) {
    union { __hip_bfloat16 h; short s; } u;
    u.h = __float2bfloat16(f);
    return u.s;
}

__global__ __launch_bounds__(256) void conv_weights(
    const float* __restrict__ W1, const float* __restrict__ W2,
    const float* __restrict__ Wp)
{
    int i = blockIdx.x * 256 + threadIdx.x;     // 81920 threads x 4 elems
    long off = (long)i * 4;
    const float* src;
    if (off < 32768)       src = W1 + off;
    else if (off < 65536)  src = W2 + (off - 32768);
    else                   src = Wp + (off - 65536);
    float4 v = *reinterpret_cast<const float4*>(src);
    short4 s;
    s.x = f2bf(v.x); s.y = f2bf(v.y); s.z = f2bf(v.z); s.w = f2bf(v.w);
    *reinterpret_cast<short4*>(g_wb + off) = s;
}

// ---- reg-staging helpers for a 16-row x 512-col bf16 tile (16 KB) ----
struct StReg { bf16x8 v[4]; };

__device__ __forceinline__ StReg stage_load(const short* __restrict__ src, int tid) {
    StReg s;
    #pragma unroll
    for (int ld = 0; ld < 4; ++ld)
        s.v[ld] = *reinterpret_cast<const bf16x8*>(
            reinterpret_cast<const char*>(src) + ld * 4096 + tid * 16);
    return s;
}

__device__ __forceinline__ void stage_write(char* buf, const StReg& s, int tid) {
    #pragma unroll
    for (int ld = 0; ld < 4; ++ld) {
        int o = ld * 4096 + tid * 16;
        int w = o ^ (((o >> 10) & 7) << 4);   // XOR-swizzle (row period 1024B)
        *reinterpret_cast<bf16x8*>(buf + w) = s.v[ld];
    }
}

// LDS offsets within the 36864-byte block (fits 4 blocks/CU: 4*36864 <= 160K)
#define WPA 0
#define WPB 16384
#define W2A 32768
#define W2B (32768 + 2048)

__global__ __launch_bounds__(256, 4) void fused_free_energy(
    const float* __restrict__ key, const float* __restrict__ value,
    const float* __restrict__ b1, const float* __restrict__ b2,
    const float* __restrict__ pb,
    float* __restrict__ outF, float* __restrict__ outPred,
    float* __restrict__ outPrec, float* __restrict__ outErr)
{
    __shared__ __align__(16) char lds[36864];

    const short* W1b = g_wb;
    const short* W2b = g_wb + 32768;
    const short* Wpb = g_wb + 65536;

    const int tid  = threadIdx.x;
    const int wave = tid >> 6;
    const int lane = tid & 63;
    const int lh   = lane & 15;
    const int lg   = lane >> 4;
    const long row0 = (long)blockIdx.x * BM;

    // ---- prologue: key rows -> bf16 register fragments (via LDS, 2 chunks of 32 rows) ----
    bf16x8 kreg[16];
    #pragma unroll
    for (int c = 0; c < 2; ++c) {
        const float4* kin = reinterpret_cast<const float4*>(key + (row0 + c * 32) * DK);
        #pragma unroll
        for (int i = 0; i < 16; ++i) {          // 32 rows x 128 float4 / 256 thr
            int idx = i * 256 + tid;
            int r = idx >> 7, c4 = idx & 127;
            float4 v = kin[idx];
            short4 s;
            s.x = f2bf(v.x); s.y = f2bf(v.y); s.z = f2bf(v.z); s.w = f2bf(v.w);
            int byte = (r * 1024 + c4 * 8) ^ ((r & 7) << 4);
            *reinterpret_cast<short4*>(lds + byte) = s;
        }
        __syncthreads();
        if ((wave >> 1) == c) {
            int rr = (wave & 1) * 16 + lh;
            #pragma unroll
            for (int kk = 0; kk < 16; ++kk) {
                int byte = (rr * 1024 + kk * 64 + lg * 16) ^ ((rr & 7) << 4);
                kreg[kk] = *reinterpret_cast<const bf16x8*>(lds + byte);
            }
        }
        __syncthreads();
    }

    const f32x4 zf = {0.f, 0.f, 0.f, 0.f};

    // ---- GEMM1: h = gelu(key @ W1^T + b1), swapped operands; h kept in regs ----
    short hs_all[16];   // h[own row][jt*16 + lg*4 + r] for jt=0..3, r=0..3
    {
        StReg st = stage_load(W1b, tid);
        stage_write(lds + WPA, st, tid);
        __syncthreads();
        #pragma unroll
        for (int jt = 0; jt < 4; ++jt) {
            char* cbuf = lds + ((jt & 1) ? WPB : WPA);
            StReg nx;
            if (jt < 3) nx = stage_load(W1b + (jt + 1) * 16 * DK, tid);
            f32x4 acc = zf;
            #pragma unroll
            for (int kk = 0; kk < 16; ++kk) {
                int byte = (lh * 1024 + kk * 64 + lg * 16) ^ ((lh & 7) << 4);
                bf16x8 af = *reinterpret_cast<const bf16x8*>(cbuf + byte);
                acc = __builtin_amdgcn_mfma_f32_16x16x32_bf16(af, kreg[kk], acc, 0, 0, 0);
            }
            float4 b1v = *reinterpret_cast<const float4*>(b1 + jt * 16 + lg * 4);
            float b1a[4] = {b1v.x, b1v.y, b1v.z, b1v.w};
            #pragma unroll
            for (int r = 0; r < 4; ++r) {
                float z = acc[r] + b1a[r];
                float g = 0.5f * z * (1.0f + erff(z * 0.70710678f));  // exact GELU
                hs_all[jt * 4 + r] = f2bf(g);
            }
            if (jt < 3) stage_write(lds + ((jt & 1) ? WPA : WPB), nx, tid);
            __syncthreads();
        }
        // park h in WPA (wave-private 2KB slots), convert to B-fragment layout
        #pragma unroll
        for (int jt = 0; jt < 4; ++jt) {
            int hb = WPA + wave * 2048 + ((lh * 128 + jt * 32 + lg * 8) ^ ((lh & 7) << 4));
            short4 hv = {hs_all[jt * 4 + 0], hs_all[jt * 4 + 1],
                         hs_all[jt * 4 + 2], hs_all[jt * 4 + 3]};
            *reinterpret_cast<short4*>(lds + hb) = hv;
        }
        __syncthreads();
    }

    bf16x8 hreg[2];
    #pragma unroll
    for (int kh = 0; kh < 2; ++kh) {
        int byte = (lh * 128 + kh * 64 + lg * 16) ^ ((lh & 7) << 4);
        hreg[kh] = *reinterpret_cast<const bf16x8*>(lds + WPA + wave * 2048 + byte);
    }
    __syncthreads();   // before main staging overwrites WPA

    // ---- main loop: 32 iterations of 16 output columns ----
    {
        StReg st = stage_load(Wpb, tid);
        const bool w2a = (tid < 128);
        bf16x8 w2r;
        if (w2a) w2r = *reinterpret_cast<const bf16x8*>(
                     reinterpret_cast<const char*>(W2b) + tid * 16);
        stage_write(lds + WPA, st, tid);
        if (w2a) {
            int o = tid * 16;
            *reinterpret_cast<bf16x8*>(lds + W2A + (o ^ (((o >> 7) & 7) << 4))) = w2r;
        }
        __syncthreads();

        float facc = 0.f;
        const long grow = row0 + wave * 16 + lh;
        float4 sv_pr, sv_pc, sv_er;           // even-iteration results (write-combine)
        long sv_ga = 0;

        for (int it = 0; it < NT; ++it) {
            char* wpc = lds + ((it & 1) ? WPB : WPA);
            char* w2c = lds + ((it & 1) ? W2B : W2A);

            // issue next-tile global loads early (hide L2 latency under compute)
            StReg nx; bf16x8 w2n;
            if (it + 1 < NT) {
                nx = stage_load(Wpb + (it + 1) * 16 * DK, tid);
                if (w2a) w2n = *reinterpret_cast<const bf16x8*>(
                             reinterpret_cast<const char*>(W2b) + (it + 1) * 2048 + tid * 16);
            }

            // GEMM3: z3 tile, A = Wp rows (n) from LDS, B = key rows (m) from regs
            f32x4 acc3 = zf;
            #pragma unroll
            for (int kk = 0; kk < 16; ++kk) {
                int byte = (lh * 1024 + kk * 64 + lg * 16) ^ ((lh & 7) << 4);
                bf16x8 af = *reinterpret_cast<const bf16x8*>(wpc + byte);
                acc3 = __builtin_amdgcn_mfma_f32_16x16x32_bf16(af, kreg[kk], acc3, 0, 0, 0);
            }
            // GEMM2: pred tile, A = W2 from LDS, B = h from regs
            f32x4 acc2 = zf;
            #pragma unroll
            for (int kh = 0; kh < 2; ++kh) {
                int byte = (lh * 128 + kh * 64 + lg * 16) ^ ((lh & 7) << 4);
                bf16x8 af = *reinterpret_cast<const bf16x8*>(w2c + byte);
                acc2 = __builtin_amdgcn_mfma_f32_16x16x32_bf16(af, hreg[kh], acc2, 0, 0, 0);
            }

            // epilogue: lane holds 4 consecutive cols (n = it*16 + lg*4 + r) of row grow
            int nb = it * 16 + lg * 4;
            float4 b2v = *reinterpret_cast<const float4*>(b2 + nb);
            float4 pbv = *reinterpret_cast<const float4*>(pb + nb);
            float b2a[4] = {b2v.x, b2v.y, b2v.z, b2v.w};
            float pba[4] = {pbv.x, pbv.y, pbv.z, pbv.w};
            long ga = grow * DV + nb;
            float4 val = *reinterpret_cast<const float4*>(value + ga);
            float va[4] = {val.x, val.y, val.z, val.w};
            float prv[4], pcv[4], erv[4];
            #pragma unroll
            for (int r = 0; r < 4; ++r) {
                float pred = acc2[r] + b2a[r];
                float z    = acc3[r] + pba[r];
                // softplus via HW exp/log: arg of log in (1,2], abs err ~1e-7
                float prec = fmaxf(z, 0.f) + __logf(1.0f + __expf(-fabsf(z))) + 0.01f;
                float err  = fminf(fmaxf(va[r] - pred, -3.f), 3.f);
                prv[r] = pred; pcv[r] = prec; erv[r] = err;
                facc += prec * err * err - __logf(prec);
            }
            float4 pr4 = {prv[0], prv[1], prv[2], prv[3]};
            float4 pc4 = {pcv[0], pcv[1], pcv[2], pcv[3]};
            float4 er4 = {erv[0], erv[1], erv[2], erv[3]};
            if ((it & 1) == 0) {
                sv_pr = pr4; sv_pc = pc4; sv_er = er4; sv_ga = ga;
            } else {
                // write both halves of each 128B line adjacently -> full-line writeback
                *reinterpret_cast<float4*>(outPred + sv_ga) = sv_pr;
                *reinterpret_cast<float4*>(outPred + ga)    = pr4;
                *reinterpret_cast<float4*>(outPrec + sv_ga) = sv_pc;
                *reinterpret_cast<float4*>(outPrec + ga)    = pc4;
                *reinterpret_cast<float4*>(outErr  + sv_ga) = sv_er;
                *reinterpret_cast<float4*>(outErr  + ga)    = er4;
            }

            // write next tile into the other buffer (its readers finished last barrier)
            if (it + 1 < NT) {
                stage_write(lds + ((it & 1) ? WPA : WPB), nx, tid);
                if (w2a) {
                    int o = tid * 16;
                    *reinterpret_cast<bf16x8*>(
                        lds + ((it & 1) ? W2A : W2B) + (o ^ (((o >> 7) & 7) << 4))) = w2n;
                }
            }
            __syncthreads();
        }

        // F: sum the 4 lg-lanes holding the same row
        facc += __shfl_xor(facc, 16, 64);
        facc += __shfl_xor(facc, 32, 64);
        if (lane < 16) outF[grow] = facc * (1.0f / 512.0f);
    }
}

extern "C" void kernel_launch(void* const* d_in, const int* in_sizes, int n_in,
                              void* d_out, int out_size, void* d_ws, size_t ws_size,
                              hipStream_t stream) {
    const float* key   = (const float*)d_in[0];
    const float* value = (const float*)d_in[1];
    const float* W1    = (const float*)d_in[2];
    const float* b1    = (const float*)d_in[3];
    const float* W2    = (const float*)d_in[4];
    const float* b2    = (const float*)d_in[5];
    const float* Wp    = (const float*)d_in[6];
    const float* pb    = (const float*)d_in[7];

    float* outF    = (float*)d_out;
    float* outPred = outF + BATCH;
    float* outPrec = outPred + (long)BATCH * DV;
    float* outErr  = outPrec + (long)BATCH * DV;

    conv_weights<<<320, 256, 0, stream>>>(W1, W2, Wp);
    fused_free_energy<<<BATCH / BM, 256, 0, stream>>>(key, value, b1, b2, pb,
                                                      outF, outPred, outPrec, outErr);
}

// Round 8
// 289.312 us; speedup vs baseline: 1.4291x; 1.4277x over previous
//
#include <hip/hip_runtime.h>
#include <hip/hip_bf16.h>

#define BATCH 65536
#define DK 512
#define DV 512
#define DH 64
#define BM 64
#define NT (DV / 16)   // 32 column-iterations

typedef __attribute__((ext_vector_type(8))) short bf16x8;
typedef __attribute__((ext_vector_type(4))) float f32x4;

// PRE-SWIZZLED bf16 weight images (LDS-ready for linear global_load_lds):
//   bytes [0, 65536):       W1, 4 tiles of 16x512 (16 KB), swizzle o^=((o>>10)&7)<<4
//   bytes [65536, 131072):  W2, 32 tiles of 16x64 (2 KB),  swizzle o^=((o>>7)&7)<<4
//   bytes [131072, 655360): Wp, 32 tiles of 16x512 (16 KB), swizzle o^=((o>>10)&7)<<4
__device__ short g_wb[327680];

__device__ __forceinline__ short f2bf(float f) {
    union { __hip_bfloat16 h; short s; } u;
    u.h = __float2bfloat16(f);
    return u.s;
}

// g_wb[x] = tile_linear[x ^ swz(x)]  (swz is an involution: XOR bits 4-6 from row bits)
__global__ __launch_bounds__(256) void conv_weights(
    const float* __restrict__ W1, const float* __restrict__ W2,
    const float* __restrict__ Wp)
{
    int t = blockIdx.x * 256 + threadIdx.x;    // 40960 threads, 16 output bytes each
    long bx = (long)t * 16;
    long inseg; const float* src; int sh;
    if (bx < 65536)       { inseg = bx;          src = W1; sh = 10; }
    else if (bx < 131072) { inseg = bx - 65536;  src = W2; sh = 7;  }
    else                  { inseg = bx - 131072; src = Wp; sh = 10; }
    long so = inseg ^ (((inseg >> sh) & 7) << 4);   // source byte offset (16B-aligned)
    const float* p = src + (so >> 1);               // bf16 byte -> f32 element index
    float4 a = *reinterpret_cast<const float4*>(p);
    float4 b = *reinterpret_cast<const float4*>(p + 4);
    bf16x8 r;
    r[0] = f2bf(a.x); r[1] = f2bf(a.y); r[2] = f2bf(a.z); r[3] = f2bf(a.w);
    r[4] = f2bf(b.x); r[5] = f2bf(b.y); r[6] = f2bf(b.z); r[7] = f2bf(b.w);
    *reinterpret_cast<bf16x8*>(reinterpret_cast<char*>(g_wb) + bx) = r;
}

// async global -> LDS, 16 B per lane; LDS dest is wave-uniform base + lane*16
__device__ __forceinline__ void gld16(const short* g, short* l) {
    __builtin_amdgcn_global_load_lds(
        (const __attribute__((address_space(1))) void*)g,
        (__attribute__((address_space(3))) void*)l, 16, 0, 0);
}

// LDS offsets within the 36864-byte block (4 blocks/CU: 4*36864 <= 160K)
#define WPA 0
#define WPB 16384
#define W2A 32768
#define W2B (32768 + 2048)

__global__ __launch_bounds__(256, 4) void fused_free_energy(
    const float* __restrict__ key, const float* __restrict__ value,
    const float* __restrict__ b1, const float* __restrict__ b2,
    const float* __restrict__ pb,
    float* __restrict__ outF, float* __restrict__ outPred,
    float* __restrict__ outPrec, float* __restrict__ outErr)
{
    __shared__ __align__(16) short ldsS[18432];   // 36864 bytes
    char* ldsb = reinterpret_cast<char*>(ldsS);

    const short* W1b = g_wb;            // pre-swizzled images
    const short* W2b = g_wb + 32768;
    const short* Wpb = g_wb + 65536;

    const int tid  = threadIdx.x;
    const int wave = tid >> 6;
    const int lane = tid & 63;
    const int lh   = lane & 15;
    const int lg   = lane >> 4;
    const long row0 = (long)blockIdx.x * BM;

    // ---- prologue: key rows -> bf16 register fragments (via LDS, 2 chunks of 32 rows) ----
    bf16x8 kreg[16];
    #pragma unroll
    for (int c = 0; c < 2; ++c) {
        const float4* kin = reinterpret_cast<const float4*>(key + (row0 + c * 32) * DK);
        #pragma unroll
        for (int i = 0; i < 16; ++i) {          // 32 rows x 128 float4 / 256 thr
            int idx = i * 256 + tid;
            int r = idx >> 7, c4 = idx & 127;
            float4 v = kin[idx];
            short4 s;
            s.x = f2bf(v.x); s.y = f2bf(v.y); s.z = f2bf(v.z); s.w = f2bf(v.w);
            int byte = (r * 1024 + c4 * 8) ^ ((r & 7) << 4);
            *reinterpret_cast<short4*>(ldsb + byte) = s;
        }
        __syncthreads();
        if ((wave >> 1) == c) {
            int rr = (wave & 1) * 16 + lh;
            #pragma unroll
            for (int kk = 0; kk < 16; ++kk) {
                int byte = (rr * 1024 + kk * 64 + lg * 16) ^ ((rr & 7) << 4);
                kreg[kk] = *reinterpret_cast<const bf16x8*>(ldsb + byte);
            }
        }
        __syncthreads();
    }

    const f32x4 zf = {0.f, 0.f, 0.f, 0.f};

    // ---- GEMM1: h = gelu(key @ W1^T + b1); W1 tiles DMA'd, double-buffered ----
    short hs_all[16];
    {
        #pragma unroll
        for (int i = 0; i < 4; ++i) {           // W1 tile 0 -> WPA
            int ch = (wave + i * 4) * 1024;
            gld16(W1b + ((ch + lane * 16) >> 1), ldsS + ((WPA + ch) >> 1));
        }
        __syncthreads();
        #pragma unroll
        for (int jt = 0; jt < 4; ++jt) {
            char* cbuf = ldsb + ((jt & 1) ? WPB : WPA);
            if (jt < 3) {
                int nb_ = (jt & 1) ? WPA : WPB;
                #pragma unroll
                for (int i = 0; i < 4; ++i) {
                    int ch = (wave + i * 4) * 1024;
                    gld16(W1b + (((jt + 1) * 16384 + ch + lane * 16) >> 1),
                          ldsS + ((nb_ + ch) >> 1));
                }
            }
            f32x4 acc = zf;
            #pragma unroll
            for (int kk = 0; kk < 16; ++kk) {
                int byte = (lh * 1024 + kk * 64 + lg * 16) ^ ((lh & 7) << 4);
                bf16x8 af = *reinterpret_cast<const bf16x8*>(cbuf + byte);
                acc = __builtin_amdgcn_mfma_f32_16x16x32_bf16(af, kreg[kk], acc, 0, 0, 0);
            }
            float4 b1v = *reinterpret_cast<const float4*>(b1 + jt * 16 + lg * 4);
            float b1a[4] = {b1v.x, b1v.y, b1v.z, b1v.w};
            #pragma unroll
            for (int r = 0; r < 4; ++r) {
                float z = acc[r] + b1a[r];
                float g = 0.5f * z * (1.0f + erff(z * 0.70710678f));  // exact GELU
                hs_all[jt * 4 + r] = f2bf(g);
            }
            __syncthreads();
        }
        // park h in WPA (wave-private 2KB slots) in B-fragment layout
        #pragma unroll
        for (int jt = 0; jt < 4; ++jt) {
            int hb = WPA + wave * 2048 + ((lh * 128 + jt * 32 + lg * 8) ^ ((lh & 7) << 4));
            short4 hv = {hs_all[jt * 4 + 0], hs_all[jt * 4 + 1],
                         hs_all[jt * 4 + 2], hs_all[jt * 4 + 3]};
            *reinterpret_cast<short4*>(ldsb + hb) = hv;
        }
        __syncthreads();
    }

    bf16x8 hreg[2];
    #pragma unroll
    for (int kh = 0; kh < 2; ++kh) {
        int byte = (lh * 128 + kh * 64 + lg * 16) ^ ((lh & 7) << 4);
        hreg[kh] = *reinterpret_cast<const bf16x8*>(ldsb + WPA + wave * 2048 + byte);
    }
    __syncthreads();   // before main staging overwrites WPA

    // ---- main loop: 32 iterations of 16 output columns; Wp/W2 tiles DMA'd ----
    {
        #pragma unroll
        for (int i = 0; i < 4; ++i) {           // Wp tile 0 -> WPA
            int ch = (wave + i * 4) * 1024;
            gld16(Wpb + ((ch + lane * 16) >> 1), ldsS + ((WPA + ch) >> 1));
        }
        if (wave < 2)                           // W2 tile 0 -> W2A
            gld16(W2b + ((wave * 1024 + lane * 16) >> 1), ldsS + ((W2A + wave * 1024) >> 1));
        __syncthreads();

        float facc = 0.f;
        const long grow = row0 + wave * 16 + lh;
        const float* vrow = value + grow * DV;
        float* prow = outPred + grow * DV;
        float* crow = outPrec + grow * DV;
        float* erow = outErr  + grow * DV;

        for (int it = 0; it < NT; ++it) {
            char* wpc = ldsb + ((it & 1) ? WPB : WPA);
            char* w2c = ldsb + ((it & 1) ? W2B : W2A);

            // issue next-tile DMA into the other buffers (hidden under this iter's compute)
            if (it + 1 < NT) {
                int nwp = (it & 1) ? WPA : WPB;
                int nw2 = (it & 1) ? W2A : W2B;
                #pragma unroll
                for (int i = 0; i < 4; ++i) {
                    int ch = (wave + i * 4) * 1024;
                    gld16(Wpb + (((it + 1) * 16384 + ch + lane * 16) >> 1),
                          ldsS + ((nwp + ch) >> 1));
                }
                if (wave < 2)
                    gld16(W2b + (((it + 1) * 2048 + wave * 1024 + lane * 16) >> 1),
                          ldsS + ((nw2 + wave * 1024) >> 1));
            }

            // GEMM3: z3 tile, A = Wp rows (n) from LDS, B = key rows (m) from regs
            f32x4 acc3 = zf;
            #pragma unroll
            for (int kk = 0; kk < 16; ++kk) {
                int byte = (lh * 1024 + kk * 64 + lg * 16) ^ ((lh & 7) << 4);
                bf16x8 af = *reinterpret_cast<const bf16x8*>(wpc + byte);
                acc3 = __builtin_amdgcn_mfma_f32_16x16x32_bf16(af, kreg[kk], acc3, 0, 0, 0);
            }
            // GEMM2: pred tile, A = W2 from LDS, B = h from regs
            f32x4 acc2 = zf;
            #pragma unroll
            for (int kh = 0; kh < 2; ++kh) {
                int byte = (lh * 128 + kh * 64 + lg * 16) ^ ((lh & 7) << 4);
                bf16x8 af = *reinterpret_cast<const bf16x8*>(w2c + byte);
                acc2 = __builtin_amdgcn_mfma_f32_16x16x32_bf16(af, hreg[kh], acc2, 0, 0, 0);
            }

            // epilogue: lane holds 4 consecutive cols (n = it*16 + lg*4 + r) of row grow
            int nb = it * 16 + lg * 4;
            float4 b2v = *reinterpret_cast<const float4*>(b2 + nb);
            float4 pbv = *reinterpret_cast<const float4*>(pb + nb);
            float4 val = *reinterpret_cast<const float4*>(vrow + nb);
            float b2a[4] = {b2v.x, b2v.y, b2v.z, b2v.w};
            float pba[4] = {pbv.x, pbv.y, pbv.z, pbv.w};
            float va[4]  = {val.x, val.y, val.z, val.w};
            float prv[4], pcv[4], erv[4];
            #pragma unroll
            for (int r = 0; r < 4; ++r) {
                float pred = acc2[r] + b2a[r];
                float z    = acc3[r] + pba[r];
                // softplus via HW exp/log: log arg in (1,2], abs err ~1e-7
                float prec = fmaxf(z, 0.f) + __logf(1.0f + __expf(-fabsf(z))) + 0.01f;
                float err  = fminf(fmaxf(va[r] - pred, -3.f), 3.f);
                prv[r] = pred; pcv[r] = prec; erv[r] = err;
                facc += prec * err * err - __logf(prec);
            }
            float4 pr4 = {prv[0], prv[1], prv[2], prv[3]};
            float4 pc4 = {pcv[0], pcv[1], pcv[2], pcv[3]};
            float4 er4 = {erv[0], erv[1], erv[2], erv[3]};
            *reinterpret_cast<float4*>(prow + nb) = pr4;
            *reinterpret_cast<float4*>(crow + nb) = pc4;
            *reinterpret_cast<float4*>(erow + nb) = er4;

            __syncthreads();   // drains DMA (vmcnt) + releases buffers
        }

        // F: sum the 4 lg-lanes holding the same row
        facc += __shfl_xor(facc, 16, 64);
        facc += __shfl_xor(facc, 32, 64);
        if (lane < 16) outF[grow] = facc * (1.0f / 512.0f);
    }
}

extern "C" void kernel_launch(void* const* d_in, const int* in_sizes, int n_in,
                              void* d_out, int out_size, void* d_ws, size_t ws_size,
                              hipStream_t stream) {
    const float* key   = (const float*)d_in[0];
    const float* value = (const float*)d_in[1];
    const float* W1    = (const float*)d_in[2];
    const float* b1    = (const float*)d_in[3];
    const float* W2    = (const float*)d_in[4];
    const float* b2    = (const float*)d_in[5];
    const float* Wp    = (const float*)d_in[6];
    const float* pb    = (const float*)d_in[7];

    float* outF    = (float*)d_out;
    float* outPred = outF + BATCH;
    float* outPrec = outPred + (long)BATCH * DV;
    float* outErr  = outPrec + (long)BATCH * DV;

    conv_weights<<<160, 256, 0, stream>>>(W1, W2, Wp);
    fused_free_energy<<<BATCH / BM, 256, 0, stream>>>(key, value, b1, b2, pb,
                                                      outF, outPred, outPrec, outErr);
}